// Round 3
// baseline (7944.407 us; speedup 1.0000x reference)
//
#include <hip/hip_runtime.h>
#include <hip/hip_bf16.h>

#define VSZ 1024   // vocab
#define HD  512    // hidden
#define NB  64     // batch
#define LQ  512    // seq len
#define G4  2048   // 4*H
#define NBLK 256   // persistent blocks (1 per CU)
#define HBUF 32768 // floats per h buffer (k-major interleaved: [k2][s*2+p])

typedef __attribute__((ext_vector_type(2))) float f32x2;

__device__ __forceinline__ float bf2f(unsigned int u16) {
  unsigned int x = u16 << 16;
  float f;
  __builtin_memcpy(&f, &x, 4);
  return f;
}

// ---------------------------------------------------------------------------
// K1: G[v][new_j] = dot(emb[v,:], W_ih[old_j,:]) + b_ih[old_j] + b_hh[old_j]
//     new_j = h_idx*4 + gate ; old_j = gate*512 + h_idx  (gate-interleaved)
// ---------------------------------------------------------------------------
__global__ __launch_bounds__(256)
void k_gtable(const float* __restrict__ emb, const float* __restrict__ Wih,
              const float* __restrict__ bih, const float* __restrict__ bhh,
              float* __restrict__ G)
{
  __shared__ float As[32][68];
  __shared__ float Bs[32][68];
  const int tid = threadIdx.x;
  const int tx = tid & 15, ty = tid >> 4;
  const int jn0 = blockIdx.x * 64;
  const int v0  = blockIdx.y * 64;
  const int lrow = tid >> 2, lkq = tid & 3;
  const int jn_l = jn0 + lrow;
  const int oldj_l = (jn_l & 3) * 512 + (jn_l >> 2);
  float acc[4][4] = {};
  for (int kc = 0; kc < HD; kc += 32) {
    const float4 a0 = *(const float4*)&emb[(v0 + lrow) * HD + kc + lkq * 8];
    const float4 a1 = *(const float4*)&emb[(v0 + lrow) * HD + kc + lkq * 8 + 4];
    const float4 b0 = *(const float4*)&Wih[oldj_l * HD + kc + lkq * 8];
    const float4 b1 = *(const float4*)&Wih[oldj_l * HD + kc + lkq * 8 + 4];
    __syncthreads();
    As[lkq*8+0][lrow] = a0.x; As[lkq*8+1][lrow] = a0.y;
    As[lkq*8+2][lrow] = a0.z; As[lkq*8+3][lrow] = a0.w;
    As[lkq*8+4][lrow] = a1.x; As[lkq*8+5][lrow] = a1.y;
    As[lkq*8+6][lrow] = a1.z; As[lkq*8+7][lrow] = a1.w;
    Bs[lkq*8+0][lrow] = b0.x; Bs[lkq*8+1][lrow] = b0.y;
    Bs[lkq*8+2][lrow] = b0.z; Bs[lkq*8+3][lrow] = b0.w;
    Bs[lkq*8+4][lrow] = b1.x; Bs[lkq*8+5][lrow] = b1.y;
    Bs[lkq*8+6][lrow] = b1.z; Bs[lkq*8+7][lrow] = b1.w;
    __syncthreads();
#pragma unroll
    for (int kk = 0; kk < 32; ++kk) {
      const float4 av = *(const float4*)&As[kk][ty*4];
      const float4 bv = *(const float4*)&Bs[kk][tx*4];
      acc[0][0] += av.x*bv.x; acc[0][1] += av.x*bv.y; acc[0][2] += av.x*bv.z; acc[0][3] += av.x*bv.w;
      acc[1][0] += av.y*bv.x; acc[1][1] += av.y*bv.y; acc[1][2] += av.y*bv.z; acc[1][3] += av.y*bv.w;
      acc[2][0] += av.z*bv.x; acc[2][1] += av.z*bv.y; acc[2][2] += av.z*bv.z; acc[2][3] += av.z*bv.w;
      acc[3][0] += av.w*bv.x; acc[3][1] += av.w*bv.y; acc[3][2] += av.w*bv.z; acc[3][3] += av.w*bv.w;
    }
  }
  float bias[4];
#pragma unroll
  for (int b = 0; b < 4; ++b) {
    const int jn = jn0 + tx*4 + b;
    const int oj = (jn & 3) * 512 + (jn >> 2);
    bias[b] = bih[oj] + bhh[oj];
  }
#pragma unroll
  for (int a = 0; a < 4; ++a) {
    const float4 st = make_float4(acc[a][0] + bias[0], acc[a][1] + bias[1],
                                  acc[a][2] + bias[2], acc[a][3] + bias[3]);
    *(float4*)&G[(v0 + ty*4 + a) * G4 + jn0 + tx*4] = st;
  }
}

// ---------------------------------------------------------------------------
// K2: init h buffer 0 (k-major interleaved), zero done flags, transpose tokens
// ---------------------------------------------------------------------------
__global__ __launch_bounds__(256)
void k_init(const float* __restrict__ ehid, const int* __restrict__ target,
            float* __restrict__ hbuf, int* __restrict__ done,
            int* __restrict__ tokT)
{
  const int i = blockIdx.x * 256 + threadIdx.x;
  if (i < NB * HD) {
    const int n = i >> 9, k = i & 511;
    hbuf[(k >> 1) * 128 + n * 2 + (k & 1)] = ehid[i];
  } else if (i < 2 * NB * HD) {
    const int j = i - NB * HD;          // j = tt*64 + s
    const int tt = j >> 6, s = j & 63;
    tokT[j] = (tt == 0) ? 0 : target[s * LQ + tt - 1];
  } else if (i < 2 * NB * HD + NBLK) {
    done[i - 2 * NB * HD] = 0;
  }
}

// ---------------------------------------------------------------------------
// K3: persistent LSTM. 256 blocks x 512 threads (8 waves). Block b owns gate
// rows 8b..8b+7. W slice + c in LDS for all 512 steps; h read directly from
// global (each element consumed once); split-k 16 groups x 32 k; pk-fma f32
// pairs; per-block monotonic done[b] flags + lane-parallel relaxed-agent
// polling (no RMW contention).
// ---------------------------------------------------------------------------
__global__ __launch_bounds__(512, 2)
void k_lstm(const float* __restrict__ G, const float* __restrict__ Whh,
            const int* __restrict__ tokT, float* __restrict__ hbuf,
            int* __restrict__ done, __hip_bfloat16* __restrict__ Hall)
{
  // 96 KB declared (forces 1 block/CU); used: W 16K @0, part 16K @4096,
  // c 512B @8192
  __shared__ float smem[24576];
  float* Wl   = smem;          // [8][512]
  float* part = smem + 4096;   // [8 waves][32 s2][16]
  float* c_l  = smem + 8192;   // [128]

  const int tid = threadIdx.x;
  const int b   = blockIdx.x;
  const int s2  = tid & 31;        // sample-pair index
  const int kq  = tid >> 5;        // k-group 0..15 (32 k each)
  const int w   = tid >> 6;        // wave 0..7

  // --- load W slice: row r = hu*4+g -> old_j = (r&3)*512 + 2b + (r>>2)
  {
    const int r = tid >> 6, cc = tid & 63;
    const int oldj = (r & 3) * 512 + 2 * b + (r >> 2);
    const float4* src = (const float4*)&Whh[(size_t)oldj * HD + cc * 8];
    float4* dst = (float4*)&Wl[r * 512 + cc * 8];
    dst[0] = src[0]; dst[1] = src[1];
  }
  if (tid < 128) c_l[tid] = 0.f;

  // --- G rows for step 0 (token 0), registers, tid<128: (s, hu)
  float4 gcur = {};
  if (tid < 128) {
    const int hu = tid & 1;
    gcur = *(const float4*)&G[(size_t)0 * G4 + b * 8 + hu * 4];
  }
  __syncthreads();

  for (int t = 0; t < LQ; ++t) {
    // ---- wait for h(t): lane-parallel poll of per-block flags
    if (tid < NBLK) {
      if (t > 0) {
        int spin = 0;
        while (__hip_atomic_load(&done[tid], __ATOMIC_RELAXED,
                                 __HIP_MEMORY_SCOPE_AGENT) < t) {
          __builtin_amdgcn_s_sleep(1);
          if (++spin > (1 << 22)) break;   // fail-safe vs hang
        }
      }
      __builtin_amdgcn_fence(__ATOMIC_ACQUIRE, "agent");
    }
    __syncthreads();

    // ---- load h slice from global: 8 chunks x 2 float4 (k-pair interleaved)
    const float* hcur = hbuf + (size_t)(t & 1) * HBUF;
    float4 ha[8], hb[8];
#pragma unroll
    for (int c = 0; c < 8; ++c) {
      const int k2 = kq * 16 + 2 * c;
      ha[c] = *(const float4*)&hcur[k2 * 128 + s2 * 4];
      hb[c] = *(const float4*)&hcur[(k2 + 1) * 128 + s2 * 4];
    }

    // ---- prefetch G rows for step t+1 (independent of h)
    float4 gnext = {};
    if (tid < 128 && t + 1 < LQ) {
      const int s = tid >> 1, hu = tid & 1;
      const int tok = tokT[(t + 1) * 64 + s];
      gnext = *(const float4*)&G[(size_t)tok * G4 + b * 8 + hu * 4];
    }

    // ---- split-k compute: (s2, kq): 2 samples x 8 rows x 32 k, pk-fma pairs
    f32x2 a2A[8], a2B[8];
#pragma unroll
    for (int r = 0; r < 8; ++r) { a2A[r] = (f32x2)0.f; a2B[r] = (f32x2)0.f; }
#pragma unroll
    for (int c = 0; c < 8; ++c) {
      const f32x2 halo = { ha[c].x, ha[c].y };   // k-pair, sample A
      const f32x2 hahi = { ha[c].z, ha[c].w };   // k-pair, sample B
      const f32x2 hblo = { hb[c].x, hb[c].y };
      const f32x2 hbhi = { hb[c].z, hb[c].w };
#pragma unroll
      for (int r = 0; r < 8; ++r) {
        const float4 wv = *(const float4*)&Wl[r * 512 + kq * 32 + c * 4];
        const f32x2 wlo = { wv.x, wv.y };
        const f32x2 whi = { wv.z, wv.w };
        a2A[r] += wlo * halo;
        a2A[r] += whi * hblo;
        a2B[r] += wlo * hahi;
        a2B[r] += whi * hbhi;
      }
    }

    // ---- reduce: horizontal k-pair, then kq-pair via shfl, park per wave
    float rA[8], rB[8];
#pragma unroll
    for (int r = 0; r < 8; ++r) {
      rA[r] = a2A[r].x + a2A[r].y;
      rB[r] = a2B[r].x + a2B[r].y;
      rA[r] += __shfl_xor(rA[r], 32, 64);
      rB[r] += __shfl_xor(rB[r], 32, 64);
    }
    if ((tid & 32) == 0) {
      float* pp = &part[w * 512 + s2 * 16];
#pragma unroll
      for (int r = 0; r < 8; ++r) { pp[r] = rA[r]; pp[8 + r] = rB[r]; }
    }
    __syncthreads();   // B1: partials visible

    // ---- cell update: 128 threads, tid = s*2 + hu
    if (tid < 128) {
      const int s = tid >> 1, hu = tid & 1;
      const float* pp = &part[4 * tid];      // = s2u*16 + p*8 + hu*4
      float v[4];
#pragma unroll
      for (int g = 0; g < 4; ++g) {
        v[g] = pp[g] + pp[512 + g] + pp[1024 + g] + pp[1536 + g]
             + pp[2048 + g] + pp[2560 + g] + pp[3072 + g] + pp[3584 + g];
      }
      const float vi = gcur.x + v[0];
      const float vf = gcur.y + v[1];
      const float vg = gcur.z + v[2];
      const float vo = gcur.w + v[3];
      const float si = 1.f / (1.f + expf(-vi));
      const float sf = 1.f / (1.f + expf(-vf));
      const float tg = tanhf(vg);
      const float so = 1.f / (1.f + expf(-vo));
      const float cn = sf * c_l[tid] + si * tg;
      const float hn = so * tanhf(cn);
      c_l[tid] = cn;
      // h layout [k2][s*2+p], k = 2b+hu -> k2 = b, slot = s*2+hu = tid
      __hip_atomic_store(&hbuf[(size_t)((t + 1) & 1) * HBUF + b * 128 + tid],
                         hn, __ATOMIC_RELAXED, __HIP_MEMORY_SCOPE_AGENT);
      Hall[((size_t)t * NB + s) * HD + 2 * b + hu] = __float2bfloat16(hn);
    }
    gcur = gnext;
    __syncthreads();   // B2: drains h stores (vmcnt 0 per wave) before flag

    if (tid == 0)
      __hip_atomic_store(&done[b], t + 1, __ATOMIC_RELAXED,
                         __HIP_MEMORY_SCOPE_AGENT);
  }
}

// ---------------------------------------------------------------------------
// K4: final hidden state (interleaved buffer 0) -> output tail [n][k]
// ---------------------------------------------------------------------------
__global__ __launch_bounds__(256)
void k_hout(const float* __restrict__ hb0, float* __restrict__ out)
{
  const int i = blockIdx.x * 256 + threadIdx.x;
  const int n = i >> 9, k = i & 511;
  out[i] = hb0[(k >> 1) * 128 + n * 2 + (k & 1)];
}

// ---------------------------------------------------------------------------
// K5: y[r][v] = dot(Hall_bf16[r,:], fc_W[v,:]) + fc_b[v]
// ---------------------------------------------------------------------------
__global__ __launch_bounds__(256)
void k_fc(const __hip_bfloat16* __restrict__ Hall, const float* __restrict__ fcW,
          const float* __restrict__ fcb, float* __restrict__ out)
{
  __shared__ float As[32][68];
  __shared__ float Bs[32][68];
  const int tid = threadIdx.x;
  const int tx = tid & 15, ty = tid >> 4;
  const int v0 = blockIdx.x * 64;
  const int r0 = blockIdx.y * 64;
  const int lrow = tid >> 2, lkq = tid & 3;
  const unsigned short* Hs = (const unsigned short*)Hall;
  float acc[4][4] = {};
  for (int kc = 0; kc < HD; kc += 32) {
    const uint4  ar = *(const uint4*)&Hs[(size_t)(r0 + lrow) * HD + kc + lkq * 8];
    const float4 b0 = *(const float4*)&fcW[(v0 + lrow) * HD + kc + lkq * 8];
    const float4 b1 = *(const float4*)&fcW[(v0 + lrow) * HD + kc + lkq * 8 + 4];
    __syncthreads();
    As[lkq*8+0][lrow] = bf2f(ar.x & 0xffffu);
    As[lkq*8+1][lrow] = bf2f(ar.x >> 16);
    As[lkq*8+2][lrow] = bf2f(ar.y & 0xffffu);
    As[lkq*8+3][lrow] = bf2f(ar.y >> 16);
    As[lkq*8+4][lrow] = bf2f(ar.z & 0xffffu);
    As[lkq*8+5][lrow] = bf2f(ar.z >> 16);
    As[lkq*8+6][lrow] = bf2f(ar.w & 0xffffu);
    As[lkq*8+7][lrow] = bf2f(ar.w >> 16);
    Bs[lkq*8+0][lrow] = b0.x; Bs[lkq*8+1][lrow] = b0.y;
    Bs[lkq*8+2][lrow] = b0.z; Bs[lkq*8+3][lrow] = b0.w;
    Bs[lkq*8+4][lrow] = b1.x; Bs[lkq*8+5][lrow] = b1.y;
    Bs[lkq*8+6][lrow] = b1.z; Bs[lkq*8+7][lrow] = b1.w;
    __syncthreads();
#pragma unroll
    for (int kk = 0; kk < 32; ++kk) {
      const float4 av = *(const float4*)&As[kk][ty*4];
      const float4 bv = *(const float4*)&Bs[kk][tx*4];
      acc[0][0] += av.x*bv.x; acc[0][1] += av.x*bv.y; acc[0][2] += av.x*bv.z; acc[0][3] += av.x*bv.w;
      acc[1][0] += av.y*bv.x; acc[1][1] += av.y*bv.y; acc[1][2] += av.y*bv.z; acc[1][3] += av.y*bv.w;
      acc[2][0] += av.z*bv.x; acc[2][1] += av.z*bv.y; acc[2][2] += av.z*bv.z; acc[2][3] += av.z*bv.w;
      acc[3][0] += av.w*bv.x; acc[3][1] += av.w*bv.y; acc[3][2] += av.w*bv.z; acc[3][3] += av.w*bv.w;
    }
  }
  const int vb = v0 + tx * 4;
  const float4 bias = *(const float4*)&fcb[vb];
#pragma unroll
  for (int a = 0; a < 4; ++a) {
    const int r = r0 + ty * 4 + a;
    const float4 st = make_float4(acc[a][0] + bias.x, acc[a][1] + bias.y,
                                  acc[a][2] + bias.z, acc[a][3] + bias.w);
    *(float4*)&out[(size_t)r * VSZ + vb] = st;
  }
}

// ---------------------------------------------------------------------------
extern "C" void kernel_launch(void* const* d_in, const int* in_sizes, int n_in,
                              void* d_out, int out_size, void* d_ws, size_t ws_size,
                              hipStream_t stream)
{
  (void)in_sizes; (void)n_in; (void)out_size; (void)ws_size;
  const float* enc_hid = (const float*)d_in[1];   // (1,64,512)
  const int*   target  = (const int*)  d_in[2];   // (64,512)
  const float* emb     = (const float*)d_in[3];   // (1024,512)
  const float* Wih     = (const float*)d_in[4];   // (2048,512)
  const float* Whh     = (const float*)d_in[5];   // (2048,512)
  const float* bih     = (const float*)d_in[6];   // (2048,)
  const float* bhh     = (const float*)d_in[7];   // (2048,)
  const float* fcW     = (const float*)d_in[8];   // (1024,512)
  const float* fcb     = (const float*)d_in[9];   // (1024,)
  float* out = (float*)d_out;

  char* ws = (char*)d_ws;
  float* G  = (float*)ws;                                    // 8 MB
  __hip_bfloat16* Hall = (__hip_bfloat16*)(ws + (8u << 20)); // 32 MB
  float* hbuf = (float*)(ws + (40u << 20));                  // 2 x 128 KB
  int*   done = (int*)(ws + (40u << 20) + (256u << 10));     // 256 ints
  int*   tokT = (int*)(ws + (40u << 20) + (257u << 10));     // 128 KB

  k_gtable<<<dim3(G4/64, VSZ/64), dim3(256), 0, stream>>>(emb, Wih, bih, bhh, G);
  k_init<<<dim3(257), dim3(256), 0, stream>>>(enc_hid, target, hbuf, done, tokT);
  k_lstm<<<dim3(NBLK), dim3(512), 0, stream>>>(G, Whh, tokT, hbuf, done, Hall);
  k_hout<<<dim3((NB*HD)/256), dim3(256), 0, stream>>>(hbuf, out + (size_t)LQ*NB*VSZ);
  k_fc<<<dim3(VSZ/64, (LQ*NB)/64), dim3(256), 0, stream>>>(Hall, fcW, fcb, out);
}

// Round 4
// 4148.009 us; speedup vs baseline: 1.9152x; 1.9152x over previous
//
#include <hip/hip_runtime.h>
#include <hip/hip_bf16.h>
#include <hip/hip_fp16.h>

#define VSZ 1024   // vocab
#define HD  512    // hidden
#define NB  64     // batch
#define LQ  512    // seq len
#define G4  2048   // 4*H
#define NBLK 16    // persistent blocks for the recurrence

typedef __attribute__((ext_vector_type(8))) _Float16 f16x8;
typedef __attribute__((ext_vector_type(4))) float    f32x4;

// ---------------------------------------------------------------------------
// K1: G[v][new_j] = dot(emb[v,:], W_ih[old_j,:]) + b_ih[old_j] + b_hh[old_j]
//     new_j = h_idx*4 + gate ; old_j = gate*512 + h_idx  (gate-interleaved)
// fp32, 64x64 tile. Runs once; G stays fp32 for exact input-path preacts.
// ---------------------------------------------------------------------------
__global__ __launch_bounds__(256)
void k_gtable(const float* __restrict__ emb, const float* __restrict__ Wih,
              const float* __restrict__ bih, const float* __restrict__ bhh,
              float* __restrict__ G)
{
  __shared__ float As[32][68];
  __shared__ float Bs[32][68];
  const int tid = threadIdx.x;
  const int tx = tid & 15, ty = tid >> 4;
  const int jn0 = blockIdx.x * 64;
  const int v0  = blockIdx.y * 64;
  const int lrow = tid >> 2, lkq = tid & 3;
  const int jn_l = jn0 + lrow;
  const int oldj_l = (jn_l & 3) * 512 + (jn_l >> 2);
  float acc[4][4] = {};
  for (int kc = 0; kc < HD; kc += 32) {
    const float4 a0 = *(const float4*)&emb[(v0 + lrow) * HD + kc + lkq * 8];
    const float4 a1 = *(const float4*)&emb[(v0 + lrow) * HD + kc + lkq * 8 + 4];
    const float4 b0 = *(const float4*)&Wih[oldj_l * HD + kc + lkq * 8];
    const float4 b1 = *(const float4*)&Wih[oldj_l * HD + kc + lkq * 8 + 4];
    __syncthreads();
    As[lkq*8+0][lrow] = a0.x; As[lkq*8+1][lrow] = a0.y;
    As[lkq*8+2][lrow] = a0.z; As[lkq*8+3][lrow] = a0.w;
    As[lkq*8+4][lrow] = a1.x; As[lkq*8+5][lrow] = a1.y;
    As[lkq*8+6][lrow] = a1.z; As[lkq*8+7][lrow] = a1.w;
    Bs[lkq*8+0][lrow] = b0.x; Bs[lkq*8+1][lrow] = b0.y;
    Bs[lkq*8+2][lrow] = b0.z; Bs[lkq*8+3][lrow] = b0.w;
    Bs[lkq*8+4][lrow] = b1.x; Bs[lkq*8+5][lrow] = b1.y;
    Bs[lkq*8+6][lrow] = b1.z; Bs[lkq*8+7][lrow] = b1.w;
    __syncthreads();
#pragma unroll
    for (int kk = 0; kk < 32; ++kk) {
      const float4 av = *(const float4*)&As[kk][ty*4];
      const float4 bv = *(const float4*)&Bs[kk][tx*4];
      acc[0][0] += av.x*bv.x; acc[0][1] += av.x*bv.y; acc[0][2] += av.x*bv.z; acc[0][3] += av.x*bv.w;
      acc[1][0] += av.y*bv.x; acc[1][1] += av.y*bv.y; acc[1][2] += av.y*bv.z; acc[1][3] += av.y*bv.w;
      acc[2][0] += av.z*bv.x; acc[2][1] += av.z*bv.y; acc[2][2] += av.z*bv.z; acc[2][3] += av.z*bv.w;
      acc[3][0] += av.w*bv.x; acc[3][1] += av.w*bv.y; acc[3][2] += av.w*bv.z; acc[3][3] += av.w*bv.w;
    }
  }
  float bias[4];
#pragma unroll
  for (int b = 0; b < 4; ++b) {
    const int jn = jn0 + tx*4 + b;
    const int oj = (jn & 3) * 512 + (jn >> 2);
    bias[b] = bih[oj] + bhh[oj];
  }
#pragma unroll
  for (int a = 0; a < 4; ++a) {
    const float4 st = make_float4(acc[a][0] + bias[0], acc[a][1] + bias[1],
                                  acc[a][2] + bias[2], acc[a][3] + bias[3]);
    *(float4*)&G[(v0 + ty*4 + a) * G4 + jn0 + tx*4] = st;
  }
}

// ---------------------------------------------------------------------------
// K2: prep — Whh -> f16 gate-interleaved Wf16[jn][k]; fcW -> f16; token
// transpose tokT[t][s]; h0 -> f16 Hst slot 0; zero flags.
// ---------------------------------------------------------------------------
__global__ __launch_bounds__(256)
void k_prep(const float* __restrict__ ehid, const int* __restrict__ target,
            const float* __restrict__ Whh, const float* __restrict__ fcW,
            _Float16* __restrict__ Wf16, _Float16* __restrict__ fcW16,
            int* __restrict__ tokT, _Float16* __restrict__ Hst,
            int* __restrict__ done)
{
  const int i = blockIdx.x * 256 + threadIdx.x;
  if (i < 131072) {                       // Wf16: 2048 rows x 64 tasks (8 k)
    const int jn = i >> 6, kq = i & 63;
    const int oldj = (jn & 3) * 512 + (jn >> 2);
    const float4 a = *(const float4*)&Whh[(size_t)oldj * HD + kq * 8];
    const float4 b = *(const float4*)&Whh[(size_t)oldj * HD + kq * 8 + 4];
    f16x8 o;
    o[0]=(_Float16)a.x; o[1]=(_Float16)a.y; o[2]=(_Float16)a.z; o[3]=(_Float16)a.w;
    o[4]=(_Float16)b.x; o[5]=(_Float16)b.y; o[6]=(_Float16)b.z; o[7]=(_Float16)b.w;
    *(f16x8*)&Wf16[(size_t)jn * HD + kq * 8] = o;
  } else if (i < 196608) {                // fcW16: 1024 rows x 64 tasks
    const int j = i - 131072;
    const int v = j >> 6, kq = j & 63;
    const float4 a = *(const float4*)&fcW[(size_t)v * HD + kq * 8];
    const float4 b = *(const float4*)&fcW[(size_t)v * HD + kq * 8 + 4];
    f16x8 o;
    o[0]=(_Float16)a.x; o[1]=(_Float16)a.y; o[2]=(_Float16)a.z; o[3]=(_Float16)a.w;
    o[4]=(_Float16)b.x; o[5]=(_Float16)b.y; o[6]=(_Float16)b.z; o[7]=(_Float16)b.w;
    *(f16x8*)&fcW16[(size_t)v * HD + kq * 8] = o;
  } else if (i < 229376) {                // tokT[t][s]
    const int j = i - 196608;
    const int tt = j >> 6, s = j & 63;
    tokT[j] = (tt == 0) ? 0 : target[s * LQ + tt - 1];
  } else if (i < 233472) {                // h0 f16 -> Hst slot 0
    const int j = i - 229376;             // 64 s x 64 tasks (8 k)
    const int s = j >> 6, kq = j & 63;
    const float4 a = *(const float4*)&ehid[(size_t)s * HD + kq * 8];
    const float4 b = *(const float4*)&ehid[(size_t)s * HD + kq * 8 + 4];
    f16x8 o;
    o[0]=(_Float16)a.x; o[1]=(_Float16)a.y; o[2]=(_Float16)a.z; o[3]=(_Float16)a.w;
    o[4]=(_Float16)b.x; o[5]=(_Float16)b.y; o[6]=(_Float16)b.z; o[7]=(_Float16)b.w;
    *(f16x8*)&Hst[(size_t)s * HD + kq * 8] = o;
  } else if (i < 233472 + NBLK) {
    done[i - 233472] = 0;
  }
}

// ---------------------------------------------------------------------------
// K3: persistent LSTM, 16 blocks x 512 threads (8 waves). Block b owns gate
// rows 128b..128b+127 (h-units 32b..32b+31). W_hh f16 fragments live in VGPRs
// (64/wave) for all 512 steps; c in VGPRs. Per step: stage h(t) 64KB f16 to
// LDS via global_load_lds with XOR-swizzled global source; 16x16x32 f16 MFMA
// (full K per wave -> no cross-wave reduce); lane-local cell update (4 gates
// in acc[0..3]); LDS transpose -> 8B write-through atomic stores of h(t+1);
// single-cache-line flag set + 16-lane ballot poll.
// ---------------------------------------------------------------------------
__global__ __launch_bounds__(512, 1)
void k_lstm(const float* __restrict__ G, const _Float16* __restrict__ Wf16,
            const int* __restrict__ tokT, _Float16* __restrict__ Hst,
            int* __restrict__ done)
{
  __shared__ __align__(16) char hlds[65536];   // h(t): [s][k] f16, XOR-swizzled
  __shared__ _Float16 hstg[64 * 32];           // h(t+1) staging: [s][hu_l]

  const int tid  = threadIdx.x;
  const int b    = blockIdx.x;
  const int w    = tid >> 6;        // wave 0..7 -> j-subtile
  const int lane = tid & 63;
  const int l15  = tid & 15;
  const int q    = (tid >> 4) & 3;  // k-group within wave

  // --- A fragments (W_hh slice) into VGPRs, once
  f16x8 afrag[16];
  {
    const _Float16* wp = Wf16 + (size_t)(b * 128 + w * 16 + l15) * HD + q * 8;
#pragma unroll
    for (int kc = 0; kc < 16; ++kc)
      afrag[kc] = *(const f16x8*)(wp + kc * 32);
  }
  const int hu_g = b * 32 + w * 4 + q;   // global h-unit this lane updates
  const int hu_l = w * 4 + q;            // local (0..31)

  float creg[4] = {0.f, 0.f, 0.f, 0.f};
  float4 gcur[4], gnext[4] = {};
#pragma unroll
  for (int st = 0; st < 4; ++st)         // step 0: token 0 for every sample
    gcur[st] = *(const float4*)&G[(size_t)0 * G4 + hu_g * 4];
  int tokn[4], tokn2[4] = {};
#pragma unroll
  for (int st = 0; st < 4; ++st)         // tokens for step 1
    tokn[st] = tokT[64 + st * 16 + l15];

  for (int t = 0; t < LQ; ++t) {
    // ---- wait for h(t): 16 lanes of wave 0 poll one flag each
    if (tid < 64) {
      if (t > 0) {
        int spin = 0;
        while (1) {
          const int v = (tid < NBLK)
              ? __hip_atomic_load(&done[tid], __ATOMIC_RELAXED,
                                  __HIP_MEMORY_SCOPE_AGENT)
              : 0x7fffffff;
          if (__all(v >= t)) break;
          if (++spin > (1 << 22)) break;   // fail-safe vs hang
        }
      }
    }
    __syncthreads();

    // ---- stage h(t) -> LDS (64KB, 8 rounds/wave), swizzled global source
    {
      const char* hsrc = (const char*)Hst + (size_t)t * 65536;
#pragma unroll
      for (int r = 0; r < 8; ++r) {
        const char* src = hsrc + (w * 8 + r) * 1024 + ((lane * 16) ^ (r << 4));
        __builtin_amdgcn_global_load_lds(
            (const __attribute__((address_space(1))) void*)src,
            (__attribute__((address_space(3))) void*)&hlds[w * 8192 + r * 1024],
            16, 0, 0);
      }
    }
    // ---- prefetch G rows for step t+1 (addresses ready: tokens prefetched)
    if (t + 1 < LQ) {
#pragma unroll
      for (int st = 0; st < 4; ++st)
        gnext[st] = *(const float4*)&G[(size_t)tokn[st] * G4 + hu_g * 4];
    }
    if (t + 2 < LQ) {
#pragma unroll
      for (int st = 0; st < 4; ++st)
        tokn2[st] = tokT[(t + 2) * 64 + st * 16 + l15];
    }
    __syncthreads();   // drains staging (vmcnt 0) + LDS visibility

    // ---- MFMA: wave computes its 16 rows x 64 samples, full K=512
    f32x4 acc[4];
#pragma unroll
    for (int st = 0; st < 4; ++st) acc[st] = (f32x4)0.f;
#pragma unroll
    for (int kc = 0; kc < 16; ++kc) {
      const int kb = kc * 64 + q * 16;   // byte offset of this lane's 8 k
#pragma unroll
      for (int st = 0; st < 4; ++st) {
        const int s = st * 16 + l15;
        const f16x8 bfrag =
            *(const f16x8*)&hlds[s * 1024 + (kb ^ ((s & 7) << 4))];
        acc[st] = __builtin_amdgcn_mfma_f32_16x16x32_f16(afrag[kc], bfrag,
                                                         acc[st], 0, 0, 0);
      }
    }

    // ---- cell update: lane-local (acc[st][0..3] = i,f,g,o for hu_g)
#pragma unroll
    for (int st = 0; st < 4; ++st) {
      const float vi = acc[st][0] + gcur[st].x;
      const float vf = acc[st][1] + gcur[st].y;
      const float vg = acc[st][2] + gcur[st].z;
      const float vo = acc[st][3] + gcur[st].w;
      const float si = 1.f / (1.f + expf(-vi));
      const float sf = 1.f / (1.f + expf(-vf));
      const float tg = tanhf(vg);
      const float so = 1.f / (1.f + expf(-vo));
      const float cn = sf * creg[st] + si * tg;
      creg[st] = cn;
      const float hn = so * tanhf(cn);
      hstg[(st * 16 + l15) * 32 + hu_l] = (_Float16)hn;
      gcur[st] = gnext[st];
      tokn[st] = tokn2[st];
    }
    __syncthreads();   // hstg visible

    // ---- h(t+1) -> global: thread s stores 64B (its 32 hu) write-through
    if (tid < 64) {
      const unsigned long long* src = (const unsigned long long*)&hstg[tid * 32];
      unsigned long long* dst = (unsigned long long*)
          ((char*)Hst + (size_t)(t + 1) * 65536 + tid * 1024 + b * 64);
#pragma unroll
      for (int u = 0; u < 8; ++u)
        __hip_atomic_store(&dst[u], src[u], __ATOMIC_RELAXED,
                           __HIP_MEMORY_SCOPE_AGENT);
    }
    __syncthreads();   // drains h stores (vmcnt 0) before flag

    if (tid == 0)
      __hip_atomic_store(&done[b], t + 1, __ATOMIC_RELAXED,
                         __HIP_MEMORY_SCOPE_AGENT);
  }
}

// ---------------------------------------------------------------------------
// K4: final hidden state (Hst slot 512, f16) -> fp32 output tail [n][k]
// ---------------------------------------------------------------------------
__global__ __launch_bounds__(256)
void k_hout(const _Float16* __restrict__ Hst, float* __restrict__ out)
{
  const int i = blockIdx.x * 256 + threadIdx.x;
  out[i] = (float)Hst[(size_t)LQ * NB * HD / 64 * 64 + i];  // 512*32768 + i
}

// ---------------------------------------------------------------------------
// K5: FC, f16 MFMA: out[r][v] = Hfc[r,:]·fcW16[v,:] + fcb[v]
// Hfc = Hst + 32768 (slots 1..512 are h_t in [r=t*64+s][k] order). 64x64 tile.
// ---------------------------------------------------------------------------
__global__ __launch_bounds__(256)
void k_fc16(const _Float16* __restrict__ Hfc, const _Float16* __restrict__ fcW16,
            const float* __restrict__ fcb, float* __restrict__ out)
{
  const int tid = threadIdx.x;
  const int w   = tid >> 6;
  const int l15 = tid & 15;
  const int q   = (tid >> 4) & 3;
  const int v0  = blockIdx.x * 64;
  const size_t r0 = (size_t)blockIdx.y * 64 + w * 16;

  const _Float16* ap = Hfc + (r0 + l15) * HD + q * 8;
  f32x4 acc[4];
#pragma unroll
  for (int st = 0; st < 4; ++st) acc[st] = (f32x4)0.f;
#pragma unroll
  for (int kc = 0; kc < 16; ++kc) {
    const f16x8 a = *(const f16x8*)(ap + kc * 32);
#pragma unroll
    for (int st = 0; st < 4; ++st) {
      const f16x8 bf = *(const f16x8*)
          &fcW16[(size_t)(v0 + st * 16 + l15) * HD + kc * 32 + q * 8];
      acc[st] = __builtin_amdgcn_mfma_f32_16x16x32_f16(a, bf, acc[st], 0, 0, 0);
    }
  }
#pragma unroll
  for (int st = 0; st < 4; ++st) {
    const int v = v0 + st * 16 + l15;
    const float bias = fcb[v];
#pragma unroll
    for (int r = 0; r < 4; ++r)
      out[(r0 + q * 4 + r) * VSZ + v] = acc[st][r] + bias;
  }
}

// ---------------------------------------------------------------------------
extern "C" void kernel_launch(void* const* d_in, const int* in_sizes, int n_in,
                              void* d_out, int out_size, void* d_ws, size_t ws_size,
                              hipStream_t stream)
{
  (void)in_sizes; (void)n_in; (void)out_size; (void)ws_size;
  const float* enc_hid = (const float*)d_in[1];   // (1,64,512)
  const int*   target  = (const int*)  d_in[2];   // (64,512)
  const float* emb     = (const float*)d_in[3];   // (1024,512)
  const float* Wih     = (const float*)d_in[4];   // (2048,512)
  const float* Whh     = (const float*)d_in[5];   // (2048,512)
  const float* bih     = (const float*)d_in[6];   // (2048,)
  const float* bhh     = (const float*)d_in[7];   // (2048,)
  const float* fcW     = (const float*)d_in[8];   // (1024,512)
  const float* fcb     = (const float*)d_in[9];   // (1024,)
  float* out = (float*)d_out;

  char* ws = (char*)d_ws;
  float*     G     = (float*)ws;                          // 8 MB
  _Float16*  Wf16  = (_Float16*)(ws + (8u << 20));        // 2 MB
  _Float16*  fcW16 = (_Float16*)(ws + (10u << 20));       // 1 MB
  int*       tokT  = (int*)(ws + (11u << 20));            // 128 KB
  int*       done  = (int*)(ws + (11u << 20) + (128u << 10)); // 64 B
  _Float16*  Hst   = (_Float16*)(ws + (12u << 20));       // 513*64KB ≈ 32.1 MB

  k_gtable<<<dim3(G4/64, VSZ/64), dim3(256), 0, stream>>>(emb, Wih, bih, bhh, G);
  k_prep<<<dim3(913), dim3(256), 0, stream>>>(enc_hid, target, Whh, fcW,
                                              Wf16, fcW16, tokT, Hst, done);
  k_lstm<<<dim3(NBLK), dim3(512), 0, stream>>>(G, Wf16, tokT, Hst, done);
  k_hout<<<dim3((NB*HD)/256), dim3(256), 0, stream>>>(Hst, out + (size_t)LQ*NB*VSZ);
  k_fc16<<<dim3(VSZ/64, (LQ*NB)/64), dim3(256), 0, stream>>>(Hst + NB*HD, fcW16,
                                                             fcb, out);
}

// Round 5
// 3494.766 us; speedup vs baseline: 2.2732x; 1.1869x over previous
//
#include <hip/hip_runtime.h>
#include <hip/hip_bf16.h>
#include <hip/hip_fp16.h>

#define VSZ 1024   // vocab
#define HD  512    // hidden
#define NB  64     // batch
#define LQ  512    // seq len
#define G4  2048   // 4*H
#define NBLK 16    // persistent blocks for the recurrence

typedef __attribute__((ext_vector_type(8))) _Float16 f16x8;
typedef __attribute__((ext_vector_type(4))) float    f32x4;

// Hst layout (f16): slot t (0..512), 64KB each, MFMA-native tiling:
//   element (t, k, s)  at  f16 offset  t*32768 + (k>>3)*512 + s*8 + (k&7)
// Producers store h directly in this order; staging is a linear copy; the
// B-frag ds_read_b128 is conflict-free (16 consecutive lanes read 256B
// contiguous).

// ---------------------------------------------------------------------------
// K1: G[v][new_j] = dot(emb[v,:], W_ih[old_j,:]) + b_ih[old_j] + b_hh[old_j]
//     new_j = h_idx*4 + gate ; old_j = gate*512 + h_idx  (gate-interleaved)
// ---------------------------------------------------------------------------
__global__ __launch_bounds__(256)
void k_gtable(const float* __restrict__ emb, const float* __restrict__ Wih,
              const float* __restrict__ bih, const float* __restrict__ bhh,
              float* __restrict__ G)
{
  __shared__ float As[32][68];
  __shared__ float Bs[32][68];
  const int tid = threadIdx.x;
  const int tx = tid & 15, ty = tid >> 4;
  const int jn0 = blockIdx.x * 64;
  const int v0  = blockIdx.y * 64;
  const int lrow = tid >> 2, lkq = tid & 3;
  const int jn_l = jn0 + lrow;
  const int oldj_l = (jn_l & 3) * 512 + (jn_l >> 2);
  float acc[4][4] = {};
  for (int kc = 0; kc < HD; kc += 32) {
    const float4 a0 = *(const float4*)&emb[(v0 + lrow) * HD + kc + lkq * 8];
    const float4 a1 = *(const float4*)&emb[(v0 + lrow) * HD + kc + lkq * 8 + 4];
    const float4 b0 = *(const float4*)&Wih[oldj_l * HD + kc + lkq * 8];
    const float4 b1 = *(const float4*)&Wih[oldj_l * HD + kc + lkq * 8 + 4];
    __syncthreads();
    As[lkq*8+0][lrow] = a0.x; As[lkq*8+1][lrow] = a0.y;
    As[lkq*8+2][lrow] = a0.z; As[lkq*8+3][lrow] = a0.w;
    As[lkq*8+4][lrow] = a1.x; As[lkq*8+5][lrow] = a1.y;
    As[lkq*8+6][lrow] = a1.z; As[lkq*8+7][lrow] = a1.w;
    Bs[lkq*8+0][lrow] = b0.x; Bs[lkq*8+1][lrow] = b0.y;
    Bs[lkq*8+2][lrow] = b0.z; Bs[lkq*8+3][lrow] = b0.w;
    Bs[lkq*8+4][lrow] = b1.x; Bs[lkq*8+5][lrow] = b1.y;
    Bs[lkq*8+6][lrow] = b1.z; Bs[lkq*8+7][lrow] = b1.w;
    __syncthreads();
#pragma unroll
    for (int kk = 0; kk < 32; ++kk) {
      const float4 av = *(const float4*)&As[kk][ty*4];
      const float4 bv = *(const float4*)&Bs[kk][tx*4];
      acc[0][0] += av.x*bv.x; acc[0][1] += av.x*bv.y; acc[0][2] += av.x*bv.z; acc[0][3] += av.x*bv.w;
      acc[1][0] += av.y*bv.x; acc[1][1] += av.y*bv.y; acc[1][2] += av.y*bv.z; acc[1][3] += av.y*bv.w;
      acc[2][0] += av.z*bv.x; acc[2][1] += av.z*bv.y; acc[2][2] += av.z*bv.z; acc[2][3] += av.z*bv.w;
      acc[3][0] += av.w*bv.x; acc[3][1] += av.w*bv.y; acc[3][2] += av.w*bv.z; acc[3][3] += av.w*bv.w;
    }
  }
  float bias[4];
#pragma unroll
  for (int b = 0; b < 4; ++b) {
    const int jn = jn0 + tx*4 + b;
    const int oj = (jn & 3) * 512 + (jn >> 2);
    bias[b] = bih[oj] + bhh[oj];
  }
#pragma unroll
  for (int a = 0; a < 4; ++a) {
    const float4 st = make_float4(acc[a][0] + bias[0], acc[a][1] + bias[1],
                                  acc[a][2] + bias[2], acc[a][3] + bias[3]);
    *(float4*)&G[(v0 + ty*4 + a) * G4 + jn0 + tx*4] = st;
  }
}

// ---------------------------------------------------------------------------
// K2: prep — Whh -> f16 gate-interleaved Wf16[jn][k]; fcW -> f16; token
// transpose tokT[t][s]; h0 -> Hst slot 0 (tiled layout); zero flags.
// ---------------------------------------------------------------------------
__global__ __launch_bounds__(256)
void k_prep(const float* __restrict__ ehid, const int* __restrict__ target,
            const float* __restrict__ Whh, const float* __restrict__ fcW,
            _Float16* __restrict__ Wf16, _Float16* __restrict__ fcW16,
            int* __restrict__ tokT, _Float16* __restrict__ Hst,
            int* __restrict__ done)
{
  const int i = blockIdx.x * 256 + threadIdx.x;
  if (i < 131072) {                       // Wf16: 2048 rows x 64 tasks (8 k)
    const int jn = i >> 6, kq = i & 63;
    const int oldj = (jn & 3) * 512 + (jn >> 2);
    const float4 a = *(const float4*)&Whh[(size_t)oldj * HD + kq * 8];
    const float4 b = *(const float4*)&Whh[(size_t)oldj * HD + kq * 8 + 4];
    f16x8 o;
    o[0]=(_Float16)a.x; o[1]=(_Float16)a.y; o[2]=(_Float16)a.z; o[3]=(_Float16)a.w;
    o[4]=(_Float16)b.x; o[5]=(_Float16)b.y; o[6]=(_Float16)b.z; o[7]=(_Float16)b.w;
    *(f16x8*)&Wf16[(size_t)jn * HD + kq * 8] = o;
  } else if (i < 196608) {                // fcW16: 1024 rows x 64 tasks
    const int j = i - 131072;
    const int v = j >> 6, kq = j & 63;
    const float4 a = *(const float4*)&fcW[(size_t)v * HD + kq * 8];
    const float4 b = *(const float4*)&fcW[(size_t)v * HD + kq * 8 + 4];
    f16x8 o;
    o[0]=(_Float16)a.x; o[1]=(_Float16)a.y; o[2]=(_Float16)a.z; o[3]=(_Float16)a.w;
    o[4]=(_Float16)b.x; o[5]=(_Float16)b.y; o[6]=(_Float16)b.z; o[7]=(_Float16)b.w;
    *(f16x8*)&fcW16[(size_t)v * HD + kq * 8] = o;
  } else if (i < 229376) {                // tokT[t][s]
    const int j = i - 196608;
    const int tt = j >> 6, s = j & 63;
    tokT[j] = (tt == 0) ? 0 : target[s * LQ + tt - 1];
  } else if (i < 233472) {                // h0 -> Hst slot 0 (tiled)
    const int j = i - 229376;             // 64 s x 64 kq
    const int s = j >> 6, kq = j & 63;
    const float4 a = *(const float4*)&ehid[(size_t)s * HD + kq * 8];
    const float4 b = *(const float4*)&ehid[(size_t)s * HD + kq * 8 + 4];
    f16x8 o;
    o[0]=(_Float16)a.x; o[1]=(_Float16)a.y; o[2]=(_Float16)a.z; o[3]=(_Float16)a.w;
    o[4]=(_Float16)b.x; o[5]=(_Float16)b.y; o[6]=(_Float16)b.z; o[7]=(_Float16)b.w;
    *(f16x8*)&Hst[(size_t)kq * 512 + s * 8] = o;
  } else if (i < 233472 + NBLK * 32) {
    done[i - 233472] = 0;
  }
}

// ---------------------------------------------------------------------------
// K3: persistent LSTM, 16 blocks x 512 threads (8 waves). Block b owns gate
// rows 128b..128b+127. W_hh f16 A-frags in VGPRs; c in VGPRs. Per step:
// linear 64KB global_load_lds of h(t); conflict-free B-frag ds_read_b128;
// 16x16x32 f16 MFMA full-K; lane-local cell update; wave0-only release
// (write-through stores + vmcnt(0) + flag); 16-lane poll w/ s_sleep backoff.
// ---------------------------------------------------------------------------
__global__ __launch_bounds__(512, 1)
void k_lstm(const float* __restrict__ G, const _Float16* __restrict__ Wf16,
            const int* __restrict__ tokT, _Float16* __restrict__ Hst,
            int* __restrict__ done)
{
  __shared__ __align__(16) char hlds[65536];   // h(t), tiled (same as global)
  __shared__ _Float16 hstg[64 * 32];           // h(t+1) staging: [s][hu_l]

  const int tid  = threadIdx.x;
  const int b    = blockIdx.x;
  const int w    = tid >> 6;        // wave 0..7 -> j-subtile
  const int lane = tid & 63;
  const int l15  = tid & 15;
  const int q    = (tid >> 4) & 3;  // lane quarter

  // --- A fragments (W_hh slice) into VGPRs, once
  f16x8 afrag[16];
  {
    const _Float16* wp = Wf16 + (size_t)(b * 128 + w * 16 + l15) * HD + q * 8;
#pragma unroll
    for (int kc = 0; kc < 16; ++kc)
      afrag[kc] = *(const f16x8*)(wp + kc * 32);
  }
  const int hu_g = b * 32 + w * 4 + q;   // global h-unit this lane updates
  const int hu_l = w * 4 + q;            // local (0..31)

  float creg[4] = {0.f, 0.f, 0.f, 0.f};
  float4 gcur[4], gnext[4] = {};
#pragma unroll
  for (int st = 0; st < 4; ++st)         // step 0: token 0 for every sample
    gcur[st] = *(const float4*)&G[(size_t)0 * G4 + hu_g * 4];
  int tokn[4], tokn2[4] = {};
#pragma unroll
  for (int st = 0; st < 4; ++st)         // tokens for step 1
    tokn[st] = tokT[64 + st * 16 + l15];

  for (int t = 0; t < LQ; ++t) {
    // ---- wait for h(t): wave 0, 16 lanes, one flag line each, backoff
    if (tid < 64) {
      if (t > 0) {
        int spin = 0;
        while (1) {
          const int v = (tid < NBLK)
              ? __hip_atomic_load(&done[tid * 32], __ATOMIC_RELAXED,
                                  __HIP_MEMORY_SCOPE_AGENT)
              : 0x7fffffff;
          if (__all(v >= t)) break;
          __builtin_amdgcn_s_sleep(1);
          if (++spin > (1 << 22)) break;   // fail-safe vs hang
        }
      }
    }
    __syncthreads();   // B0: poll done

    // ---- stage h(t) -> LDS: linear 64KB copy (8 rounds/wave)
    {
      const char* hsrc = (const char*)Hst + (size_t)t * 65536 + w * 8192;
      char* ldst = &hlds[w * 8192];
#pragma unroll
      for (int r = 0; r < 8; ++r) {
        __builtin_amdgcn_global_load_lds(
            (const __attribute__((address_space(1))) void*)
                (hsrc + r * 1024 + lane * 16),
            (__attribute__((address_space(3))) void*)(ldst + r * 1024),
            16, 0, 0);
      }
    }
    // ---- prefetch G rows for step t+1 (tokens already in regs)
    if (t + 1 < LQ) {
#pragma unroll
      for (int st = 0; st < 4; ++st)
        gnext[st] = *(const float4*)&G[(size_t)tokn[st] * G4 + hu_g * 4];
    }
    if (t + 2 < LQ) {
#pragma unroll
      for (int st = 0; st < 4; ++st)
        tokn2[st] = tokT[(t + 2) * 64 + st * 16 + l15];
    }
    __syncthreads();   // B1: drains staging (vmcnt 0 per wave)

    // ---- MFMA: wave computes its 16 gate rows x 64 samples, full K=512
    f32x4 acc[4];
#pragma unroll
    for (int st = 0; st < 4; ++st) acc[st] = (f32x4)0.f;
#pragma unroll
    for (int kc = 0; kc < 16; ++kc) {
      const int rowb = (kc * 4 + q) * 1024;   // tile base (bytes)
#pragma unroll
      for (int st = 0; st < 4; ++st) {
        const int s = st * 16 + l15;
        const f16x8 bfrag = *(const f16x8*)&hlds[rowb + s * 16];
        acc[st] = __builtin_amdgcn_mfma_f32_16x16x32_f16(afrag[kc], bfrag,
                                                         acc[st], 0, 0, 0);
      }
    }

    // ---- cell update: lane-local (acc[st][0..3] = i,f,g,o for hu_g)
#pragma unroll
    for (int st = 0; st < 4; ++st) {
      const float vi = acc[st][0] + gcur[st].x;
      const float vf = acc[st][1] + gcur[st].y;
      const float vg = acc[st][2] + gcur[st].z;
      const float vo = acc[st][3] + gcur[st].w;
      const float si = 1.f / (1.f + expf(-vi));
      const float sf = 1.f / (1.f + expf(-vf));
      const float tg = tanhf(vg);
      const float so = 1.f / (1.f + expf(-vo));
      const float cn = sf * creg[st] + si * tg;
      creg[st] = cn;
      const float hn = so * tanhf(cn);
      hstg[(st * 16 + l15) * 32 + hu_l] = (_Float16)hn;
      gcur[st] = gnext[st];
      tokn[st] = tokn2[st];
    }
    __syncthreads();   // B2: hstg visible to wave 0

    // ---- release: wave 0 stores h(t+1) (tiled, write-through) + flag
    if (tid < 64) {
      const unsigned long long* src =
          (const unsigned long long*)&hstg[tid * 32];
      char* dstb = (char*)Hst + (size_t)(t + 1) * 65536 + b * 4096 + tid * 16;
#pragma unroll
      for (int u = 0; u < 4; ++u) {
        unsigned long long* d = (unsigned long long*)(dstb + u * 1024);
        __hip_atomic_store(&d[0], src[u * 2 + 0], __ATOMIC_RELAXED,
                           __HIP_MEMORY_SCOPE_AGENT);
        __hip_atomic_store(&d[1], src[u * 2 + 1], __ATOMIC_RELAXED,
                           __HIP_MEMORY_SCOPE_AGENT);
      }
      asm volatile("s_waitcnt vmcnt(0)" ::: "memory");
      if (tid == 0)
        __hip_atomic_store(&done[b * 32], t + 1, __ATOMIC_RELAXED,
                           __HIP_MEMORY_SCOPE_AGENT);
    }
  }
}

// ---------------------------------------------------------------------------
// K4: final hidden state (Hst slot 512, tiled) -> fp32 output tail [n][k]
// ---------------------------------------------------------------------------
__global__ __launch_bounds__(256)
void k_hout(const _Float16* __restrict__ Hst, float* __restrict__ out)
{
  const int i = blockIdx.x * 256 + threadIdx.x;
  const int n = i >> 9, k = i & 511;
  out[i] = (float)Hst[(size_t)512 * 32768 + (k >> 3) * 512 + n * 8 + (k & 7)];
}

// ---------------------------------------------------------------------------
// K5: FC, f16 MFMA: out[r][v] = h_t[s,:]·fcW16[v,:] + fcb[v], r = t*64+s.
// A-frags read from tiled Hst slot t+1 (16B coalesced).
// ---------------------------------------------------------------------------
__global__ __launch_bounds__(256)
void k_fc16(const _Float16* __restrict__ Hst, const _Float16* __restrict__ fcW16,
            const float* __restrict__ fcb, float* __restrict__ out)
{
  const int tid = threadIdx.x;
  const int w   = tid >> 6;
  const int l15 = tid & 15;
  const int q   = (tid >> 4) & 3;
  const int v0  = blockIdx.x * 64;
  const int ty  = blockIdx.y;            // t = ty; rows r = ty*64 + s
  const size_t slotf = (size_t)(ty + 1) * 32768;
  const int s = w * 16 + l15;

  f32x4 acc[4];
#pragma unroll
  for (int st = 0; st < 4; ++st) acc[st] = (f32x4)0.f;
#pragma unroll
  for (int kc = 0; kc < 16; ++kc) {
    const f16x8 a = *(const f16x8*)&Hst[slotf + (kc * 4 + q) * 512 + s * 8];
#pragma unroll
    for (int st = 0; st < 4; ++st) {
      const f16x8 bf = *(const f16x8*)
          &fcW16[(size_t)(v0 + st * 16 + l15) * HD + kc * 32 + q * 8];
      acc[st] = __builtin_amdgcn_mfma_f32_16x16x32_f16(a, bf, acc[st], 0, 0, 0);
    }
  }
#pragma unroll
  for (int st = 0; st < 4; ++st) {
    const int v = v0 + st * 16 + l15;
    const float bias = fcb[v];
#pragma unroll
    for (int r = 0; r < 4; ++r)
      out[(size_t)(ty * 64 + w * 16 + q * 4 + r) * VSZ + v] = acc[st][r] + bias;
  }
}

// ---------------------------------------------------------------------------
extern "C" void kernel_launch(void* const* d_in, const int* in_sizes, int n_in,
                              void* d_out, int out_size, void* d_ws, size_t ws_size,
                              hipStream_t stream)
{
  (void)in_sizes; (void)n_in; (void)out_size; (void)ws_size;
  const float* enc_hid = (const float*)d_in[1];   // (1,64,512)
  const int*   target  = (const int*)  d_in[2];   // (64,512)
  const float* emb     = (const float*)d_in[3];   // (1024,512)
  const float* Wih     = (const float*)d_in[4];   // (2048,512)
  const float* Whh     = (const float*)d_in[5];   // (2048,512)
  const float* bih     = (const float*)d_in[6];   // (2048,)
  const float* bhh     = (const float*)d_in[7];   // (2048,)
  const float* fcW     = (const float*)d_in[8];   // (1024,512)
  const float* fcb     = (const float*)d_in[9];   // (1024,)
  float* out = (float*)d_out;

  char* ws = (char*)d_ws;
  float*     G     = (float*)ws;                          // 8 MB
  _Float16*  Wf16  = (_Float16*)(ws + (8u << 20));        // 2 MB
  _Float16*  fcW16 = (_Float16*)(ws + (10u << 20));       // 1 MB
  int*       tokT  = (int*)(ws + (11u << 20));            // 128 KB
  int*       done  = (int*)(ws + (11u << 20) + (128u << 10)); // 2 KB
  _Float16*  Hst   = (_Float16*)(ws + (12u << 20));       // 513*64KB ≈ 32.1 MB

  k_gtable<<<dim3(G4/64, VSZ/64), dim3(256), 0, stream>>>(emb, Wih, bih, bhh, G);
  k_prep<<<dim3(914), dim3(256), 0, stream>>>(enc_hid, target, Whh, fcW,
                                              Wf16, fcW16, tokT, Hst, done);
  k_lstm<<<dim3(NBLK), dim3(512), 0, stream>>>(G, Wf16, tokT, Hst, done);
  k_hout<<<dim3((NB*HD)/256), dim3(256), 0, stream>>>(Hst, out + (size_t)LQ*NB*VSZ);
  k_fc16<<<dim3(VSZ/64, LQ), dim3(256), 0, stream>>>(Hst, fcW16, fcb, out);
}

// Round 6
// 2640.546 us; speedup vs baseline: 3.0086x; 1.3235x over previous
//
#include <hip/hip_runtime.h>
#include <hip/hip_bf16.h>
#include <hip/hip_fp16.h>

#define VSZ 1024   // vocab
#define HD  512    // hidden
#define NB  64     // batch
#define LQ  512    // seq len
#define G4  2048   // 4*H
#define NBLK 16    // persistent blocks for the recurrence

typedef __attribute__((ext_vector_type(8))) _Float16 f16x8;
typedef __attribute__((ext_vector_type(4))) float    f32x4;

// Hst layout (f16): slot t (0..512), 64KB each, MFMA-native tiling:
//   element (t, k, s)  at  f16 offset  t*32768 + (k>>3)*512 + s*8 + (k&7)
// Producer block b owns k in [32b, 32b+32) -> its slice is rows 4b..4b+3
// (4KB contiguous). Consumer wave w stages rows 8w..8w+7 = producers 2w,2w+1.

__device__ __forceinline__ float fexp2(float x) {
  float r; asm("v_exp_f32 %0, %1" : "=v"(r) : "v"(x)); return r;
}
__device__ __forceinline__ float frcp(float x) {
  float r; asm("v_rcp_f32 %0, %1" : "=v"(r) : "v"(x)); return r;
}
__device__ __forceinline__ float fsigmoid(float x) {
  return frcp(1.f + fexp2(-1.44269504f * x));
}
__device__ __forceinline__ float ftanh(float x) {
  return 2.f * frcp(1.f + fexp2(-2.88539008f * x)) - 1.f;
}

// ---------------------------------------------------------------------------
// K1: G[v][new_j] = dot(emb[v,:], W_ih[old_j,:]) + b_ih[old_j] + b_hh[old_j]
//     new_j = h_idx*4 + gate ; old_j = gate*512 + h_idx  (gate-interleaved)
// ---------------------------------------------------------------------------
__global__ __launch_bounds__(256)
void k_gtable(const float* __restrict__ emb, const float* __restrict__ Wih,
              const float* __restrict__ bih, const float* __restrict__ bhh,
              float* __restrict__ G)
{
  __shared__ float As[32][68];
  __shared__ float Bs[32][68];
  const int tid = threadIdx.x;
  const int tx = tid & 15, ty = tid >> 4;
  const int jn0 = blockIdx.x * 64;
  const int v0  = blockIdx.y * 64;
  const int lrow = tid >> 2, lkq = tid & 3;
  const int jn_l = jn0 + lrow;
  const int oldj_l = (jn_l & 3) * 512 + (jn_l >> 2);
  float acc[4][4] = {};
  for (int kc = 0; kc < HD; kc += 32) {
    const float4 a0 = *(const float4*)&emb[(v0 + lrow) * HD + kc + lkq * 8];
    const float4 a1 = *(const float4*)&emb[(v0 + lrow) * HD + kc + lkq * 8 + 4];
    const float4 b0 = *(const float4*)&Wih[oldj_l * HD + kc + lkq * 8];
    const float4 b1 = *(const float4*)&Wih[oldj_l * HD + kc + lkq * 8 + 4];
    __syncthreads();
    As[lkq*8+0][lrow] = a0.x; As[lkq*8+1][lrow] = a0.y;
    As[lkq*8+2][lrow] = a0.z; As[lkq*8+3][lrow] = a0.w;
    As[lkq*8+4][lrow] = a1.x; As[lkq*8+5][lrow] = a1.y;
    As[lkq*8+6][lrow] = a1.z; As[lkq*8+7][lrow] = a1.w;
    Bs[lkq*8+0][lrow] = b0.x; Bs[lkq*8+1][lrow] = b0.y;
    Bs[lkq*8+2][lrow] = b0.z; Bs[lkq*8+3][lrow] = b0.w;
    Bs[lkq*8+4][lrow] = b1.x; Bs[lkq*8+5][lrow] = b1.y;
    Bs[lkq*8+6][lrow] = b1.z; Bs[lkq*8+7][lrow] = b1.w;
    __syncthreads();
#pragma unroll
    for (int kk = 0; kk < 32; ++kk) {
      const float4 av = *(const float4*)&As[kk][ty*4];
      const float4 bv = *(const float4*)&Bs[kk][tx*4];
      acc[0][0] += av.x*bv.x; acc[0][1] += av.x*bv.y; acc[0][2] += av.x*bv.z; acc[0][3] += av.x*bv.w;
      acc[1][0] += av.y*bv.x; acc[1][1] += av.y*bv.y; acc[1][2] += av.y*bv.z; acc[1][3] += av.y*bv.w;
      acc[2][0] += av.z*bv.x; acc[2][1] += av.z*bv.y; acc[2][2] += av.z*bv.z; acc[2][3] += av.z*bv.w;
      acc[3][0] += av.w*bv.x; acc[3][1] += av.w*bv.y; acc[3][2] += av.w*bv.z; acc[3][3] += av.w*bv.w;
    }
  }
  float bias[4];
#pragma unroll
  for (int b = 0; b < 4; ++b) {
    const int jn = jn0 + tx*4 + b;
    const int oj = (jn & 3) * 512 + (jn >> 2);
    bias[b] = bih[oj] + bhh[oj];
  }
#pragma unroll
  for (int a = 0; a < 4; ++a) {
    const float4 st = make_float4(acc[a][0] + bias[0], acc[a][1] + bias[1],
                                  acc[a][2] + bias[2], acc[a][3] + bias[3]);
    *(float4*)&G[(v0 + ty*4 + a) * G4 + jn0 + tx*4] = st;
  }
}

// ---------------------------------------------------------------------------
// K2: prep — Whh -> f16 gate-interleaved Wf16[jn][k]; fcW -> f16; token
// transpose tokT[t][s]; h0 -> Hst slot 0 (tiled layout); zero flags.
// (kernel-end flush makes all of this visible to k_lstm's L2-bypass reads)
// ---------------------------------------------------------------------------
__global__ __launch_bounds__(256)
void k_prep(const float* __restrict__ ehid, const int* __restrict__ target,
            const float* __restrict__ Whh, const float* __restrict__ fcW,
            _Float16* __restrict__ Wf16, _Float16* __restrict__ fcW16,
            int* __restrict__ tokT, _Float16* __restrict__ Hst,
            int* __restrict__ done)
{
  const int i = blockIdx.x * 256 + threadIdx.x;
  if (i < 131072) {                       // Wf16: 2048 rows x 64 tasks (8 k)
    const int jn = i >> 6, kq = i & 63;
    const int oldj = (jn & 3) * 512 + (jn >> 2);
    const float4 a = *(const float4*)&Whh[(size_t)oldj * HD + kq * 8];
    const float4 b = *(const float4*)&Whh[(size_t)oldj * HD + kq * 8 + 4];
    f16x8 o;
    o[0]=(_Float16)a.x; o[1]=(_Float16)a.y; o[2]=(_Float16)a.z; o[3]=(_Float16)a.w;
    o[4]=(_Float16)b.x; o[5]=(_Float16)b.y; o[6]=(_Float16)b.z; o[7]=(_Float16)b.w;
    *(f16x8*)&Wf16[(size_t)jn * HD + kq * 8] = o;
  } else if (i < 196608) {                // fcW16: 1024 rows x 64 tasks
    const int j = i - 131072;
    const int v = j >> 6, kq = j & 63;
    const float4 a = *(const float4*)&fcW[(size_t)v * HD + kq * 8];
    const float4 b = *(const float4*)&fcW[(size_t)v * HD + kq * 8 + 4];
    f16x8 o;
    o[0]=(_Float16)a.x; o[1]=(_Float16)a.y; o[2]=(_Float16)a.z; o[3]=(_Float16)a.w;
    o[4]=(_Float16)b.x; o[5]=(_Float16)b.y; o[6]=(_Float16)b.z; o[7]=(_Float16)b.w;
    *(f16x8*)&fcW16[(size_t)v * HD + kq * 8] = o;
  } else if (i < 229376) {                // tokT[t][s]
    const int j = i - 196608;
    const int tt = j >> 6, s = j & 63;
    tokT[j] = (tt == 0) ? 0 : target[s * LQ + tt - 1];
  } else if (i < 233472) {                // h0 -> Hst slot 0 (tiled)
    const int j = i - 229376;             // 64 s x 64 kq
    const int s = j >> 6, kq = j & 63;
    const float4 a = *(const float4*)&ehid[(size_t)s * HD + kq * 8];
    const float4 b = *(const float4*)&ehid[(size_t)s * HD + kq * 8 + 4];
    f16x8 o;
    o[0]=(_Float16)a.x; o[1]=(_Float16)a.y; o[2]=(_Float16)a.z; o[3]=(_Float16)a.w;
    o[4]=(_Float16)b.x; o[5]=(_Float16)b.y; o[6]=(_Float16)b.z; o[7]=(_Float16)b.w;
    *(f16x8*)&Hst[(size_t)kq * 512 + s * 8] = o;
  } else if (i < 233472 + NBLK * 32) {
    done[i - 233472] = 0;
  }
}

// ---------------------------------------------------------------------------
// K3: persistent LSTM, 16 blocks x 512 threads (8 waves). Block b owns gate
// rows 128b..128b+127. W_hh f16 A-frags in VGPRs; c in VGPRs. Per step:
// per-wave poll of its 2 producers -> per-wave 8KB agent-scope (aux=16,
// L2-bypass) global_load_lds; B1; G/token prefetch (hidden under MFMA);
// 16x16x32 f16 MFMA full-K; lane-local cell update (fast exp2 sigmoid/tanh);
// B2; wave0 write-through release + vmcnt(0) + flag. No L2-invalidating
// fence anywhere -> G/tokens/W stay L2-hot.
// ---------------------------------------------------------------------------
__global__ __launch_bounds__(512, 1)
void k_lstm(const float* __restrict__ G, const _Float16* __restrict__ Wf16,
            const int* __restrict__ tokT, _Float16* __restrict__ Hst,
            int* __restrict__ done)
{
  __shared__ __align__(16) char hlds[65536];   // h(t), tiled (same as global)
  __shared__ _Float16 hstg[64 * 36];           // h(t+1) staging: [s][pad 36]

  const int tid  = threadIdx.x;
  const int b    = blockIdx.x;
  const int w    = tid >> 6;        // wave 0..7 -> j-subtile / producer pair
  const int lane = tid & 63;
  const int l15  = tid & 15;
  const int q    = (tid >> 4) & 3;  // lane quarter

  // --- A fragments (W_hh slice) into VGPRs, once
  f16x8 afrag[16];
  {
    const _Float16* wp = Wf16 + (size_t)(b * 128 + w * 16 + l15) * HD + q * 8;
#pragma unroll
    for (int kc = 0; kc < 16; ++kc)
      afrag[kc] = *(const f16x8*)(wp + kc * 32);
  }
  const int hu_g = b * 32 + w * 4 + q;   // global h-unit this lane updates
  const int hu_l = w * 4 + q;            // local (0..31)

  float creg[4] = {0.f, 0.f, 0.f, 0.f};
  float4 gcur[4];
#pragma unroll
  for (int st = 0; st < 4; ++st)         // step 0: token 0 for every sample
    gcur[st] = *(const float4*)&G[(size_t)0 * G4 + hu_g * 4];
  int tokn[4];
#pragma unroll
  for (int st = 0; st < 4; ++st)         // tokens for step 1
    tokn[st] = tokT[64 + st * 16 + l15];

  for (int t = 0; t < LQ; ++t) {
    // ---- per-wave: wait for this wave's 2 producers, then stage its 8KB
    if (t > 0) {
      int spin = 0;
      while (1) {
        const int v = (lane < 2)
            ? __hip_atomic_load(&done[(w * 2 + lane) * 32], __ATOMIC_RELAXED,
                                __HIP_MEMORY_SCOPE_AGENT)
            : 0x7fffffff;
        if (__all(v >= t)) break;
        __builtin_amdgcn_s_sleep(1);
        if (++spin > (1 << 22)) break;   // fail-safe vs hang
      }
    }
    {
      const char* hsrc = (const char*)Hst + (size_t)t * 65536 + w * 8192;
      char* ldst = &hlds[w * 8192];
#pragma unroll
      for (int r = 0; r < 8; ++r) {
        __builtin_amdgcn_global_load_lds(
            (const __attribute__((address_space(1))) void*)
                (hsrc + r * 1024 + lane * 16),
            (__attribute__((address_space(3))) void*)(ldst + r * 1024),
            16, 0, 16 /* SC1: agent-scope, bypass non-coherent L2 */);
      }
    }
    __syncthreads();   // B1: all staging drained (vmcnt 0 per wave)

    // ---- G/token prefetch for t+1 (issued now; latency hides under MFMA)
    float4 gnext[4] = {};
    int tokn2[4] = {};
    if (t + 1 < LQ) {
#pragma unroll
      for (int st = 0; st < 4; ++st)
        gnext[st] = *(const float4*)&G[(size_t)tokn[st] * G4 + hu_g * 4];
    }
    if (t + 2 < LQ) {
#pragma unroll
      for (int st = 0; st < 4; ++st)
        tokn2[st] = tokT[(t + 2) * 64 + st * 16 + l15];
    }

    // ---- MFMA: wave computes its 16 gate rows x 64 samples, full K=512
    f32x4 acc[4];
#pragma unroll
    for (int st = 0; st < 4; ++st) acc[st] = (f32x4)0.f;
#pragma unroll
    for (int kc = 0; kc < 16; ++kc) {
      const int rowb = (kc * 4 + q) * 1024;   // tile base (bytes)
#pragma unroll
      for (int st = 0; st < 4; ++st) {
        const int s = st * 16 + l15;
        const f16x8 bfrag = *(const f16x8*)&hlds[rowb + s * 16];
        acc[st] = __builtin_amdgcn_mfma_f32_16x16x32_f16(afrag[kc], bfrag,
                                                         acc[st], 0, 0, 0);
      }
    }

    // ---- cell update: lane-local (acc[st][0..3] = i,f,g,o for hu_g)
#pragma unroll
    for (int st = 0; st < 4; ++st) {
      const float vi = acc[st][0] + gcur[st].x;
      const float vf = acc[st][1] + gcur[st].y;
      const float vg = acc[st][2] + gcur[st].z;
      const float vo = acc[st][3] + gcur[st].w;
      const float si = fsigmoid(vi);
      const float sf = fsigmoid(vf);
      const float tg = ftanh(vg);
      const float so = fsigmoid(vo);
      const float cn = sf * creg[st] + si * tg;
      creg[st] = cn;
      const float hn = so * ftanh(cn);
      hstg[(st * 16 + l15) * 36 + hu_l] = (_Float16)hn;
      gcur[st] = gnext[st];
      tokn[st] = tokn2[st];
    }
    __syncthreads();   // B2: hstg visible to wave 0; protects hlds reuse

    // ---- release: wave 0 stores h(t+1) (tiled, write-through) + flag
    if (tid < 64) {
      const unsigned long long* src =
          (const unsigned long long*)&hstg[tid * 36];
      char* dstb = (char*)Hst + (size_t)(t + 1) * 65536 + b * 4096 + tid * 16;
#pragma unroll
      for (int u = 0; u < 4; ++u) {
        unsigned long long* d = (unsigned long long*)(dstb + u * 1024);
        __hip_atomic_store(&d[0], src[u * 2 + 0], __ATOMIC_RELAXED,
                           __HIP_MEMORY_SCOPE_AGENT);
        __hip_atomic_store(&d[1], src[u * 2 + 1], __ATOMIC_RELAXED,
                           __HIP_MEMORY_SCOPE_AGENT);
      }
      asm volatile("s_waitcnt vmcnt(0)" ::: "memory");
      if (tid == 0)
        __hip_atomic_store(&done[b * 32], t + 1, __ATOMIC_RELAXED,
                           __HIP_MEMORY_SCOPE_AGENT);
    }
  }
}

// ---------------------------------------------------------------------------
// K4: final hidden state (Hst slot 512, tiled) -> fp32 output tail [n][k]
// ---------------------------------------------------------------------------
__global__ __launch_bounds__(256)
void k_hout(const _Float16* __restrict__ Hst, float* __restrict__ out)
{
  const int i = blockIdx.x * 256 + threadIdx.x;
  const int n = i >> 9, k = i & 511;
  out[i] = (float)Hst[(size_t)512 * 32768 + (k >> 3) * 512 + n * 8 + (k & 7)];
}

// ---------------------------------------------------------------------------
// K5: FC, f16 MFMA: out[r][v] = h_t[s,:]·fcW16[v,:] + fcb[v], r = t*64+s.
// A-frags read from tiled Hst slot t+1 (16B coalesced).
// ---------------------------------------------------------------------------
__global__ __launch_bounds__(256)
void k_fc16(const _Float16* __restrict__ Hst, const _Float16* __restrict__ fcW16,
            const float* __restrict__ fcb, float* __restrict__ out)
{
  const int tid = threadIdx.x;
  const int w   = tid >> 6;
  const int l15 = tid & 15;
  const int q   = (tid >> 4) & 3;
  const int v0  = blockIdx.x * 64;
  const int ty  = blockIdx.y;            // t = ty; rows r = ty*64 + s
  const size_t slotf = (size_t)(ty + 1) * 32768;
  const int s = w * 16 + l15;

  f32x4 acc[4];
#pragma unroll
  for (int st = 0; st < 4; ++st) acc[st] = (f32x4)0.f;
#pragma unroll
  for (int kc = 0; kc < 16; ++kc) {
    const f16x8 a = *(const f16x8*)&Hst[slotf + (kc * 4 + q) * 512 + s * 8];
#pragma unroll
    for (int st = 0; st < 4; ++st) {
      const f16x8 bf = *(const f16x8*)
          &fcW16[(size_t)(v0 + st * 16 + l15) * HD + kc * 32 + q * 8];
      acc[st] = __builtin_amdgcn_mfma_f32_16x16x32_f16(a, bf, acc[st], 0, 0, 0);
    }
  }
#pragma unroll
  for (int st = 0; st < 4; ++st) {
    const int v = v0 + st * 16 + l15;
    const float bias = fcb[v];
#pragma unroll
    for (int r = 0; r < 4; ++r)
      out[(size_t)(ty * 64 + w * 16 + q * 4 + r) * VSZ + v] = acc[st][r] + bias;
  }
}

// ---------------------------------------------------------------------------
extern "C" void kernel_launch(void* const* d_in, const int* in_sizes, int n_in,
                              void* d_out, int out_size, void* d_ws, size_t ws_size,
                              hipStream_t stream)
{
  (void)in_sizes; (void)n_in; (void)out_size; (void)ws_size;
  const float* enc_hid = (const float*)d_in[1];   // (1,64,512)
  const int*   target  = (const int*)  d_in[2];   // (64,512)
  const float* emb     = (const float*)d_in[3];   // (1024,512)
  const float* Wih     = (const float*)d_in[4];   // (2048,512)
  const float* Whh     = (const float*)d_in[5];   // (2048,512)
  const float* bih     = (const float*)d_in[6];   // (2048,)
  const float* bhh     = (const float*)d_in[7];   // (2048,)
  const float* fcW     = (const float*)d_in[8];   // (1024,512)
  const float* fcb     = (const float*)d_in[9];   // (1024,)
  float* out = (float*)d_out;

  char* ws = (char*)d_ws;
  float*     G     = (float*)ws;                          // 8 MB
  _Float16*  Wf16  = (_Float16*)(ws + (8u << 20));        // 2 MB
  _Float16*  fcW16 = (_Float16*)(ws + (10u << 20));       // 1 MB
  int*       tokT  = (int*)(ws + (11u << 20));            // 128 KB
  int*       done  = (int*)(ws + (11u << 20) + (128u << 10)); // 2 KB
  _Float16*  Hst   = (_Float16*)(ws + (12u << 20));       // 513*64KB ≈ 32.1 MB

  k_gtable<<<dim3(G4/64, VSZ/64), dim3(256), 0, stream>>>(emb, Wih, bih, bhh, G);
  k_prep<<<dim3(914), dim3(256), 0, stream>>>(enc_hid, target, Whh, fcW,
                                              Wf16, fcW16, tokT, Hst, done);
  k_lstm<<<dim3(NBLK), dim3(512), 0, stream>>>(G, Wf16, tokT, Hst, done);
  k_hout<<<dim3((NB*HD)/256), dim3(256), 0, stream>>>(Hst, out + (size_t)LQ*NB*VSZ);
  k_fc16<<<dim3(VSZ/64, LQ), dim3(256), 0, stream>>>(Hst, fcW16, fcb, out);
}